// Round 1
// baseline (2409.827 us; speedup 1.0000x reference)
//
#include <hip/hip_runtime.h>
#include <math.h>

#define Tn 64
#define Bn 256
#define Hn 256
#define Vn 10000

// ---------------------------------------------------------------------------
// whT[n][k] = wh[k][n]   (wh is [256][768], whT is [768][256])
// ---------------------------------------------------------------------------
__global__ __launch_bounds__(256) void k_transpose_wh(const float* __restrict__ wh,
                                                      float* __restrict__ whT) {
    int n = blockIdx.x;      // 0..767
    int k = threadIdx.x;     // 0..255
    whT[n * 256 + k] = wh[k * 768 + n];
}

// ---------------------------------------------------------------------------
// Generic fp32 tiled GEMM, C[M,N] = A[M,256] @ B[256,N] (+bias variants)
// BM=BN=64, BK=64 (4 k-tiles), 256 threads, 4x4 micro-tile.
// MODE 0: A row = poi_emb[x[m]],      bias = gru_b[n],          N=768 (no guard)
// MODE 1: A row = user_emb[gidx[m]],  bias = fc_b[n],           N=10000 (guard)
// MODE 2: A row = Abase + m*256,      bias = UC[(m&255)*N + n], N=10000 (guard)
// ---------------------------------------------------------------------------
template <int MODE>
__global__ __launch_bounds__(256) void k_gemm(const float* __restrict__ Abase,
                                              const int* __restrict__ gidx,
                                              const float* __restrict__ Bg,
                                              const float* __restrict__ bias,
                                              float* __restrict__ C,
                                              int N, int ldb, int koff) {
    __shared__ float As[64][64];   // As[k][m] (A transposed in LDS)
    __shared__ float Bs[64][64];   // Bs[k][n]

    const int tid = threadIdx.x;
    const int m0 = blockIdx.y * 64;
    const int n0 = blockIdx.x * 64;

    // A staging assignment: each thread owns row m_l, k-quad kq
    const int m_l = tid & 63;
    const int kq = tid >> 6;       // 0..3
    long arow;
    if (MODE == 2) arow = (long)(m0 + m_l);
    else           arow = (long)gidx[m0 + m_l];
    const float* Ap = Abase + arow * 256;

    // B staging assignment
    const int nc = tid & 15;
    const int kr0 = tid >> 4;      // 0..15

    const int ty = tid >> 4, tx = tid & 15;

    float acc[4][4];
#pragma unroll
    for (int r = 0; r < 4; ++r)
#pragma unroll
        for (int c = 0; c < 4; ++c) acc[r][c] = 0.f;

    for (int k0 = 0; k0 < 256; k0 += 64) {
        // stage A -> As[k][m]
#pragma unroll
        for (int i = 0; i < 4; ++i) {
            int kc = kq + i * 4;   // 0..15
            float4 a4 = *(const float4*)(Ap + k0 + kc * 4);
            As[kc * 4 + 0][m_l] = a4.x;
            As[kc * 4 + 1][m_l] = a4.y;
            As[kc * 4 + 2][m_l] = a4.z;
            As[kc * 4 + 3][m_l] = a4.w;
        }
        // stage B -> Bs[k][n]
#pragma unroll
        for (int i = 0; i < 4; ++i) {
            int kr = kr0 + i * 16;        // 0..63
            int col = n0 + nc * 4;
            float4 b4;
            if (MODE == 0 || col < N) {
                b4 = *(const float4*)(Bg + (long)(koff + k0 + kr) * ldb + col);
            } else {
                b4 = make_float4(0.f, 0.f, 0.f, 0.f);
            }
            *(float4*)&Bs[kr][nc * 4] = b4;
        }
        __syncthreads();
#pragma unroll
        for (int kk = 0; kk < 64; ++kk) {
            float4 a4 = *(const float4*)&As[kk][ty * 4];
            float4 b4 = *(const float4*)&Bs[kk][tx * 4];
            acc[0][0] += a4.x * b4.x; acc[0][1] += a4.x * b4.y;
            acc[0][2] += a4.x * b4.z; acc[0][3] += a4.x * b4.w;
            acc[1][0] += a4.y * b4.x; acc[1][1] += a4.y * b4.y;
            acc[1][2] += a4.y * b4.z; acc[1][3] += a4.y * b4.w;
            acc[2][0] += a4.z * b4.x; acc[2][1] += a4.z * b4.y;
            acc[2][2] += a4.z * b4.z; acc[2][3] += a4.z * b4.w;
            acc[3][0] += a4.w * b4.x; acc[3][1] += a4.w * b4.y;
            acc[3][2] += a4.w * b4.z; acc[3][3] += a4.w * b4.w;
        }
        __syncthreads();
    }

    // epilogue
#pragma unroll
    for (int r = 0; r < 4; ++r) {
        int m = m0 + ty * 4 + r;
#pragma unroll
        for (int c = 0; c < 4; ++c) {
            int n = n0 + tx * 4 + c;
            if (MODE == 0) {
                C[(long)m * N + n] = acc[r][c] + bias[n];
            } else if (MODE == 1) {
                if (n < N) C[(long)m * N + n] = acc[r][c] + bias[n];
            } else {
                if (n < N) C[(long)m * N + n] = acc[r][c] + bias[(long)(m & 255) * N + n];
            }
        }
    }
}

// ---------------------------------------------------------------------------
// One GRU step: hout[b,h] for a 16x16 (b,h) tile per block.
// gh = hprev @ wh (via whT in LDS), gates fused.
// ---------------------------------------------------------------------------
__global__ __launch_bounds__(256) void k_gru_step(const float* __restrict__ gx,    // [B,768] (this t)
                                                  const float* __restrict__ hprev, // [B,256]
                                                  const float* __restrict__ whT,   // [768,256]
                                                  float* __restrict__ hout) {      // [B,256]
    __shared__ float hs[16][260];   // hprev rows (full K), padded
    __shared__ float ws[48][260];   // whT rows for r/z/n gate columns of this h-tile

    const int tid = threadIdx.x;
    const int h0 = blockIdx.x * 16;
    const int b0 = blockIdx.y * 16;

#pragma unroll
    for (int i = 0; i < 4; ++i) {
        int idx = tid + i * 256;
        int row = idx >> 6, c4 = idx & 63;
        *(float4*)&hs[row][c4 * 4] = *(const float4*)(hprev + (b0 + row) * 256 + c4 * 4);
    }
#pragma unroll
    for (int i = 0; i < 12; ++i) {
        int idx = tid + i * 256;
        int row = idx >> 6, c4 = idx & 63;     // row 0..47
        int g = row >> 4, hh = row & 15;       // gate, col-in-tile
        *(float4*)&ws[row][c4 * 4] = *(const float4*)(whT + (g * 256 + h0 + hh) * 256 + c4 * 4);
    }
    __syncthreads();

    const int tb = tid >> 4, th = tid & 15;
    float ra = 0.f, za = 0.f, na = 0.f;
#pragma unroll 16
    for (int k4 = 0; k4 < 64; ++k4) {
        float4 h4 = *(const float4*)&hs[tb][k4 * 4];
        float4 wr = *(const float4*)&ws[th][k4 * 4];
        float4 wz = *(const float4*)&ws[16 + th][k4 * 4];
        float4 wn = *(const float4*)&ws[32 + th][k4 * 4];
        ra += h4.x * wr.x + h4.y * wr.y + h4.z * wr.z + h4.w * wr.w;
        za += h4.x * wz.x + h4.y * wz.y + h4.z * wz.z + h4.w * wz.w;
        na += h4.x * wn.x + h4.y * wn.y + h4.z * wn.z + h4.w * wn.w;
    }
    const int b = b0 + tb, h = h0 + th;
    float gxr = gx[b * 768 + h];
    float gxz = gx[b * 768 + 256 + h];
    float gxn = gx[b * 768 + 512 + h];
    float hp = hs[tb][h];
    float r = 1.f / (1.f + expf(-(gxr + ra)));
    float z = 1.f / (1.f + expf(-(gxz + za)));
    float nn = tanhf(gxn + r * na);
    hout[b * 256 + h] = (1.f - z) * nn + z * hp;
}

// ---------------------------------------------------------------------------
// Spatio-temporal weights + causal weighted average. One block per batch b.
// ---------------------------------------------------------------------------
__global__ __launch_bounds__(256) void k_stw(const float* __restrict__ t_in,  // [T,B]
                                             const float* __restrict__ s_in,  // [T,B,2]
                                             const float* __restrict__ OUT,   // [T,B,H]
                                             float* __restrict__ OUTW) {      // [T,B,H]
    __shared__ float tl[64];
    __shared__ float sl[64][2];
    __shared__ float w[64][64];
    __shared__ float swinv[64];
    __shared__ float outc[16][256];

    const int b = blockIdx.x;
    const int tid = threadIdx.x;

    if (tid < 64) tl[tid] = t_in[tid * Bn + b];
    if (tid < 128) {
        int i = tid >> 1, c = tid & 1;
        sl[i][c] = s_in[(i * Bn + b) * 2 + c];
    }
    __syncthreads();

    const float TWO_PI_OVER_DAY = 6.283185307179586f / 86400.0f;
    const float LT_OVER_DAY = 0.1f / 86400.0f;
#pragma unroll
    for (int e = tid; e < 4096; e += 256) {
        int i = e >> 6, j = e & 63;
        float v = 0.f;
        if (j <= i) {
            float dt = tl[i] - tl[j];
            float dx = sl[i][0] - sl[j][0];
            float dy = sl[i][1] - sl[j][1];
            float dsd = sqrtf(dx * dx + dy * dy);
            float ft = 0.5f * (cosf(dt * TWO_PI_OVER_DAY) + 1.f) * expf(-dt * LT_OVER_DAY);
            float fs = expf(-dsd * 100.0f);
            v = ft * fs + 1e-10f;
        }
        w[i][j] = v;
    }
    __syncthreads();
    if (tid < 64) {
        float s = 0.f;
        for (int j = 0; j <= tid; ++j) s += w[tid][j];
        swinv[tid] = 1.f / s;
    }
    __syncthreads();

    // out_w[i,b,h] = (1/sw[i]) * sum_{j<=i} w[i][j] * OUT[j,b,h]; thread owns h=tid
    for (int it = 0; it < 4; ++it) {
        float accs[16];
#pragma unroll
        for (int q = 0; q < 16; ++q) accs[q] = 0.f;
        for (int jt = 0; jt <= it; ++jt) {
            __syncthreads();   // protect previous outc readers
#pragma unroll
            for (int i2 = 0; i2 < 4; ++i2) {
                int idx = tid + i2 * 256;
                int jr = idx >> 6, c4 = idx & 63;
                *(float4*)&outc[jr][c4 * 4] =
                    *(const float4*)(OUT + ((long)(jt * 16 + jr) * Bn + b) * Hn + c4 * 4);
            }
            __syncthreads();
#pragma unroll
            for (int i_l = 0; i_l < 16; ++i_l) {
                int i = it * 16 + i_l;
                int jmax = (jt < it) ? 15 : i_l;
                float a = accs[i_l];
                for (int j_l = 0; j_l <= jmax; ++j_l)
                    a += w[i][jt * 16 + j_l] * outc[j_l][tid];
                accs[i_l] = a;
            }
        }
#pragma unroll
        for (int i_l = 0; i_l < 16; ++i_l) {
            int i = it * 16 + i_l;
            OUTW[((long)i * Bn + b) * Hn + tid] = accs[i_l] * swinv[i];
        }
    }
}

// ---------------------------------------------------------------------------
__global__ __launch_bounds__(256) void k_copy4(const float* __restrict__ src,
                                               float* __restrict__ dst, int n4) {
    int i = blockIdx.x * 256 + threadIdx.x;
    if (i < n4) ((float4*)dst)[i] = ((const float4*)src)[i];
}

// ---------------------------------------------------------------------------
extern "C" void kernel_launch(void* const* d_in, const int* in_sizes, int n_in,
                              void* d_out, int out_size, void* d_ws, size_t ws_size,
                              hipStream_t stream) {
    const int*   x     = (const int*)  d_in[0];
    const float* t_in  = (const float*)d_in[1];
    const float* s_in  = (const float*)d_in[2];
    const float* h0    = (const float*)d_in[3];
    const int*   auser = (const int*)  d_in[4];
    const float* poi   = (const float*)d_in[5];
    const float* uemb  = (const float*)d_in[6];
    const float* wx    = (const float*)d_in[7];
    const float* wh    = (const float*)d_in[8];
    const float* gb    = (const float*)d_in[9];
    const float* fcw   = (const float*)d_in[10];
    const float* fcb   = (const float*)d_in[11];

    float* GX   = (float*)d_ws;                 // [T,B,768]   12,582,912 f
    float* OUT  = GX + (long)Tn * Bn * 768;     // [T,B,256]    4,194,304 f
    float* OUTW = OUT + (long)Tn * Bn * Hn;     // [T,B,256]    4,194,304 f
    float* UC   = OUTW + (long)Tn * Bn * Hn;    // [B,V]        2,560,000 f
    float* WHT  = UC + (long)Bn * Vn;           // [768,256]      196,608 f

    float* y    = (float*)d_out;                       // [T,B,V]
    float* hfin = y + (long)Tn * Bn * Vn;              // [B,H]

    k_transpose_wh<<<768, 256, 0, stream>>>(wh, WHT);

    // GX = poi_emb[x] @ wx + gru_b   (M=16384, N=768, K=256)
    k_gemm<0><<<dim3(12, 256), 256, 0, stream>>>(poi, x, wx, gb, GX, 768, 768, 0);

    // UC = user_emb[active_user] @ fc_w[256:512] + fc_b   (M=256, N=10000, K=256)
    k_gemm<1><<<dim3(157, 4), 256, 0, stream>>>(uemb, auser, fcw, fcb, UC, Vn, Vn, 256);

    // GRU recurrence
    for (int t = 0; t < Tn; ++t) {
        const float* hp = (t == 0) ? h0 : (OUT + (long)(t - 1) * Bn * Hn);
        k_gru_step<<<dim3(16, 16), 256, 0, stream>>>(GX + (long)t * Bn * 768, hp, WHT,
                                                     OUT + (long)t * Bn * Hn);
    }
    // h_final
    k_copy4<<<64, 256, 0, stream>>>(OUT + (long)(Tn - 1) * Bn * Hn, hfin, (Bn * Hn) / 4);

    // causal spatio-temporal weighted average
    k_stw<<<256, 256, 0, stream>>>(t_in, s_in, OUT, OUTW);

    // y = OUTW @ fc_w[0:256] + UC[b]   (M=16384, N=10000, K=256)
    k_gemm<2><<<dim3(157, 256), 256, 0, stream>>>(OUTW, nullptr, fcw, UC, y, Vn, Vn, 0);
}